// Round 6
// baseline (181.746 us; speedup 1.0000x reference)
//
#include <hip/hip_runtime.h>
#include <math.h>

#define BB 8192
#define DD 4096
#define EE 64

constexpr float NOISE_EPS = 0.01f;
constexpr int BM = 32;              // rows per block
constexpr int BK = 32;              // K per MFMA step
constexpr int NT = DD / BK;         // 128
constexpr int WR = 128;             // weight rows (64 gw + 64 ngw)

typedef __attribute__((ext_vector_type(8))) _Float16 f16x8;
typedef __attribute__((ext_vector_type(2))) _Float16 f16x2;
typedef __attribute__((ext_vector_type(4))) float    f32x4;

// ---------- pre-pass: split weights into fp16 hi/mid planes in ws ----------
// ws layout: [plane 0=hi,1=mid][row 0..127][k 0..4095] fp16 ; rows 64.. = ngw
__global__ __launch_bounds__(256) void wsplit_kernel(
    const float* __restrict__ gw, const float* __restrict__ ngw,
    _Float16* __restrict__ ws)
{
    const int gid = blockIdx.x * 256 + threadIdx.x;   // pair id, 262144 total
    const int row = gid >> 11;                        // 0..127
    const int k   = (gid & 2047) * 2;
    const float* src = (row < EE) ? gw + (size_t)row * DD + k
                                  : ngw + (size_t)(row - EE) * DD + k;
    float2 v = *reinterpret_cast<const float2*>(src);
    _Float16 h0 = (_Float16)v.x, h1 = (_Float16)v.y;      // RN
    f16x2 hi = {h0, h1};
    f16x2 mi = {(_Float16)(v.x - (float)h0), (_Float16)(v.y - (float)h1)};
    *reinterpret_cast<f16x2*>(ws + (size_t)row * DD + k) = hi;
    *reinterpret_cast<f16x2*>(ws + (size_t)WR * DD + (size_t)row * DD + k) = mi;
}

__device__ __forceinline__ void split8(const float4& a, const float4& b,
                                       f16x8& hi, f16x8& mi) {
    float v[8] = {a.x, a.y, a.z, a.w, b.x, b.y, b.z, b.w};
    #pragma unroll
    for (int j = 0; j < 8; ++j) {
        _Float16 h = (_Float16)v[j];          // RN
        hi[j] = h;
        mi[j] = (_Float16)(v[j] - (float)h);
    }
}

// ---------------------------- main fused kernel ----------------------------
// No LDS / no barriers in the K-loop: A and B fragments are loaded directly
// from global (x: HBM + register split; w: presplit fp16 planes, L2-resident).
template <bool PRESPLIT>
__global__ __launch_bounds__(512) void gating_kernel(
    const float* __restrict__ x,      // [B, D]
    const float* __restrict__ gw,     // [E, D]  (fallback only)
    const float* __restrict__ ngw,    // [E, D]  (fallback only)
    const _Float16* __restrict__ wsp, // [2][128][4096] fp16 (presplit)
    const float* __restrict__ noise,  // [B, E]
    float* __restrict__ out)          // gates [B,E] then load [B,E]
{
    __shared__ float lg[BM][132];     // logits tile for epilogue only (~16.9 KB)

    const int tid  = threadIdx.x;
    const int row0 = blockIdx.x * BM;
    const int lane = tid & 63;
    const int wv   = tid >> 6;          // 8 waves: 2M x 4N
    const int wmi  = wv >> 2;           // 0..1
    const int wni  = wv & 3;            // 0..3
    const int l15  = lane & 15;
    const int kq   = lane >> 4;         // k-group: 8 consecutive k per lane

    // A: this lane's fragment rows/k in x
    const float* xp = x + (size_t)(row0 + wmi * 16 + l15) * DD + kq * 8;

    // B: two col-groups (16 cols each) x two planes from presplit ws
    const int c0row = wni * 32 + l15;         // col-group 0 weight row
    const int c1row = c0row + 16;             // col-group 1 weight row
    const _Float16* wb00 = wsp + (size_t)c0row * DD + kq * 8;                    // hi,c0
    const _Float16* wb01 = wsp + (size_t)c1row * DD + kq * 8;                    // hi,c1
    const _Float16* wb10 = wsp + (size_t)(WR + c0row) * DD + kq * 8;             // mid,c0
    const _Float16* wb11 = wsp + (size_t)(WR + c1row) * DD + kq * 8;             // mid,c1

    // fallback: fp32 weight rows
    const float* fw0 = ((c0row < EE) ? gw + (size_t)c0row * DD
                                     : ngw + (size_t)(c0row - EE) * DD) + kq * 8;
    const float* fw1 = ((c1row < EE) ? gw + (size_t)c1row * DD
                                     : ngw + (size_t)(c1row - EE) * DD) + kq * 8;

    f32x4 acc0 = {0.f, 0.f, 0.f, 0.f};
    f32x4 acc1 = {0.f, 0.f, 0.f, 0.f};

    // register pipeline: x dist-2 (HBM), w dist-1 (L2)
    float4 xc0, xc1, xn0, xn1, x20, x21;
    f16x8 bh0, bh1, bm0, bm1;            // current w frags
    f16x8 nh0, nh1, nm0, nm1;            // next w frags

    auto LOADW = [&](int t, f16x8& h0, f16x8& h1, f16x8& m0, f16x8& m1) {
        if constexpr (PRESPLIT) {
            h0 = *reinterpret_cast<const f16x8*>(wb00 + (size_t)t * BK);
            h1 = *reinterpret_cast<const f16x8*>(wb01 + (size_t)t * BK);
            m0 = *reinterpret_cast<const f16x8*>(wb10 + (size_t)t * BK);
            m1 = *reinterpret_cast<const f16x8*>(wb11 + (size_t)t * BK);
        } else {
            float4 a0 = *reinterpret_cast<const float4*>(fw0 + (size_t)t * BK);
            float4 a1 = *reinterpret_cast<const float4*>(fw0 + (size_t)t * BK + 4);
            float4 b0 = *reinterpret_cast<const float4*>(fw1 + (size_t)t * BK);
            float4 b1 = *reinterpret_cast<const float4*>(fw1 + (size_t)t * BK + 4);
            split8(a0, a1, h0, m0);
            split8(b0, b1, h1, m1);
        }
    };

    // ---- prologue ----
    LOADW(0, bh0, bh1, bm0, bm1);
    xc0 = *reinterpret_cast<const float4*>(xp);
    xc1 = *reinterpret_cast<const float4*>(xp + 4);
    xn0 = *reinterpret_cast<const float4*>(xp + BK);
    xn1 = *reinterpret_cast<const float4*>(xp + BK + 4);

    // ---- main loop: no barriers, no LDS ----
    for (int t = 0; t < NT; ++t) {
        if (t + 1 < NT) LOADW(t + 1, nh0, nh1, nm0, nm1);
        if (t + 2 < NT) {
            x20 = *reinterpret_cast<const float4*>(xp + (size_t)(t + 2) * BK);
            x21 = *reinterpret_cast<const float4*>(xp + (size_t)(t + 2) * BK + 4);
        }

        f16x8 ah, am;
        split8(xc0, xc1, ah, am);

        acc0 = __builtin_amdgcn_mfma_f32_16x16x32_f16(ah, bh0, acc0, 0, 0, 0);
        acc1 = __builtin_amdgcn_mfma_f32_16x16x32_f16(ah, bh1, acc1, 0, 0, 0);
        acc0 = __builtin_amdgcn_mfma_f32_16x16x32_f16(am, bh0, acc0, 0, 0, 0);
        acc1 = __builtin_amdgcn_mfma_f32_16x16x32_f16(am, bh1, acc1, 0, 0, 0);
        acc0 = __builtin_amdgcn_mfma_f32_16x16x32_f16(ah, bm0, acc0, 0, 0, 0);
        acc1 = __builtin_amdgcn_mfma_f32_16x16x32_f16(ah, bm1, acc1, 0, 0, 0);
        acc0 = __builtin_amdgcn_mfma_f32_16x16x32_f16(am, bm0, acc0, 0, 0, 0);
        acc1 = __builtin_amdgcn_mfma_f32_16x16x32_f16(am, bm1, acc1, 0, 0, 0);

        xc0 = xn0; xc1 = xn1; xn0 = x20; xn1 = x21;
        bh0 = nh0; bh1 = nh1; bm0 = nm0; bm1 = nm1;
    }

    // ---- accumulators -> logits tile ----
    {
        const int rb = wmi * 16 + kq * 4;
        const int c0 = wni * 32 + l15;
        #pragma unroll
        for (int j = 0; j < 4; ++j) {
            lg[rb + j][c0]      = acc0[j];
            lg[rb + j][c0 + 16] = acc1[j];
        }
    }
    __syncthreads();

    // ---- parallel epilogue: wave wv owns rows 4wv..4wv+3; 16 lanes/row ----
    {
        const int r    = wv * 4 + kq;        // row in tile
        const int s    = l15;                // 16-lane slot; experts 4s..4s+3
        const int grow = row0 + r;

        float4 nz = *reinterpret_cast<const float4*>(noise + (size_t)grow * EE + 4 * s);

        float cc[4];
        float m1 = -3.4e38f, m2 = -3.4e38f;
        int   i1 = -1, i2 = -1;
        float cmax = -3.4e38f;
        #pragma unroll
        for (int j = 0; j < 4; ++j) {
            const int e = 4 * s + j;
            float c  = lg[r][e];
            float nl = lg[r][EE + e];
            cc[j] = c;
            float sp  = fmaxf(nl, 0.0f) + log1pf(expf(-fabsf(nl)));  // softplus
            float nzj = (j == 0) ? nz.x : (j == 1) ? nz.y : (j == 2) ? nz.z : nz.w;
            float vno = fmaf(nzj * sp, NOISE_EPS, c);
            if (vno > m1)      { m2 = m1; i2 = i1; m1 = vno; i1 = e; }
            else if (vno > m2) { m2 = vno; i2 = e; }
            cmax = fmaxf(cmax, c);
        }

        // 16-lane reduce: top-2 with (value, lower-index) tiebreak + clean max
        #pragma unroll
        for (int m = 1; m < 16; m <<= 1) {
            float b1 = __shfl_xor(m1, m, 16);
            int  bi1 = __shfl_xor(i1, m, 16);
            float b2 = __shfl_xor(m2, m, 16);
            int  bi2 = __shfl_xor(i2, m, 16);
            cmax = fmaxf(cmax, __shfl_xor(cmax, m, 16));

            bool bwin = (b1 > m1) || (b1 == m1 && bi1 < i1);
            float t1; int ti1; float t2; int ti2;
            if (bwin) {
                t1 = b1; ti1 = bi1;
                bool aw = (m1 > b2) || (m1 == b2 && i1 < bi2);
                t2 = aw ? m1 : b2; ti2 = aw ? i1 : bi2;
            } else {
                t1 = m1; ti1 = i1;
                bool bw = (b1 > m2) || (b1 == m2 && bi1 < i2);
                t2 = bw ? b1 : m2; ti2 = bw ? bi1 : i2;
            }
            m1 = t1; i1 = ti1; m2 = t2; i2 = ti2;
        }

        float tq = expf(m2 - m1);
        float p1 = 1.0f / (1.0f + tq);
        float p2 = tq * p1;

        float e0 = expf(cc[0] - cmax);
        float e1 = expf(cc[1] - cmax);
        float e2 = expf(cc[2] - cmax);
        float e3 = expf(cc[3] - cmax);
        float sum = e0 + e1 + e2 + e3;
        #pragma unroll
        for (int m = 1; m < 16; m <<= 1) sum += __shfl_xor(sum, m, 16);
        float inv = 1.0f / sum;

        const int eb = 4 * s;
        float4 gt;
        gt.x = (eb     == i1) ? p1 : (eb     == i2) ? p2 : 0.0f;
        gt.y = (eb + 1 == i1) ? p1 : (eb + 1 == i2) ? p2 : 0.0f;
        gt.z = (eb + 2 == i1) ? p1 : (eb + 2 == i2) ? p2 : 0.0f;
        gt.w = (eb + 3 == i1) ? p1 : (eb + 3 == i2) ? p2 : 0.0f;
        float4 ld = {e0 * inv, e1 * inv, e2 * inv, e3 * inv};

        *reinterpret_cast<float4*>(out + (size_t)grow * EE + eb) = gt;
        *reinterpret_cast<float4*>(out + (size_t)BB * EE + (size_t)grow * EE + eb) = ld;
    }
}

extern "C" void kernel_launch(void* const* d_in, const int* in_sizes, int n_in,
                              void* d_out, int out_size, void* d_ws, size_t ws_size,
                              hipStream_t stream) {
    const float* x     = (const float*)d_in[0];
    const float* gw    = (const float*)d_in[1];
    const float* ngw   = (const float*)d_in[2];
    const float* noise = (const float*)d_in[3];
    float* out = (float*)d_out;

    const size_t need = (size_t)2 * WR * DD * sizeof(_Float16);   // 2 MB
    if (ws_size >= need) {
        _Float16* ws = (_Float16*)d_ws;
        hipLaunchKernelGGL(wsplit_kernel, dim3(WR * DD / 2 / 256), dim3(256), 0, stream,
                           gw, ngw, ws);
        hipLaunchKernelGGL(gating_kernel<true>, dim3(BB / BM), dim3(512), 0, stream,
                           x, gw, ngw, ws, noise, out);
    } else {
        hipLaunchKernelGGL(gating_kernel<false>, dim3(BB / BM), dim3(512), 0, stream,
                           x, gw, ngw, (const _Float16*)d_ws, noise, out);
    }
}

// Round 7
// 54.809 us; speedup vs baseline: 3.3160x; 3.3160x over previous
//
#include <hip/hip_runtime.h>
#include <math.h>

#define BB 8192
#define DD 4096
#define EE 64

constexpr float NOISE_EPS = 0.01f;
constexpr int BM  = 64;             // rows per block (main GEMM)
constexpr int BK  = 32;             // K per step (one MFMA K)
constexpr int WRN = 128;            // weight rows total (64 gw + 64 ngw)

typedef __attribute__((ext_vector_type(8))) _Float16 f16x8;
typedef __attribute__((ext_vector_type(4))) float    f32x4;

__device__ __forceinline__ void split8(const float4& a, const float4& b,
                                       f16x8& hi, f16x8& mi) {
    float v[8] = {a.x, a.y, a.z, a.w, b.x, b.y, b.z, b.w};
    #pragma unroll
    for (int j = 0; j < 8; ++j) {
        _Float16 h = (_Float16)v[j];          // RN
        hi[j] = h;
        mi[j] = (_Float16)(v[j] - (float)h);
    }
}

__device__ __forceinline__ void gl_lds16(const void* g, void* l) {
    __builtin_amdgcn_global_load_lds(
        (const __attribute__((address_space(1))) unsigned*)g,
        (__attribute__((address_space(3))) unsigned*)l, 16, 0, 0);
}

// ---- pre-pass: pack weights into fp16 hi/mid planes in FRAGMENT order ----
// wpk chunk T (16 KB, T = global k-step): [cb 0..7][plane 0..1][lane 0..63] x 16B
// content(cb,p,lane): 8 fp16, weight row cb*16+(lane&15), k = T*32+(lane>>4)*8..
__global__ __launch_bounds__(256) void wsplit_pack(
    const float* __restrict__ gw, const float* __restrict__ ngw,
    char* __restrict__ wpk)
{
    const int gid = blockIdx.x * 256 + threadIdx.x;   // 65536 threads
    const int r   = gid >> 9;                         // 0..127
    const int kc  = gid & 511;                        // 8-float chunk in row
    const int k0  = kc * 8;
    const float* src = (r < EE) ? gw + (size_t)r * DD + k0
                                : ngw + (size_t)(r - EE) * DD + k0;
    float4 a = *reinterpret_cast<const float4*>(src);
    float4 b = *reinterpret_cast<const float4*>(src + 4);
    f16x8 hi, mi;
    split8(a, b, hi, mi);
    const int T    = k0 >> 5;
    const int kq   = (k0 >> 3) & 3;
    const int cb   = r >> 4;
    const int lane = kq * 16 + (r & 15);
    char* base = wpk + (size_t)T * 16384;
    *reinterpret_cast<f16x8*>(base + ((cb * 2 + 0) * 64 + lane) * 16) = hi;
    *reinterpret_cast<f16x8*>(base + ((cb * 2 + 1) * 64 + lane) * 16) = mi;
}

// ------------------------------- main GEMM --------------------------------
// grid = (BB/BM) * SK blocks, 512 threads. Counted-vmcnt double-buffered
// global_load_lds pipeline, raw s_barrier (no vmcnt(0) drain in loop).
template <int SK>
__global__ __launch_bounds__(512, 4) void gating_main(
    const float* __restrict__ x,
    const char*  __restrict__ wpk,
    float* __restrict__ partial)       // [SK][BB][128]
{
    constexpr int KC  = DD / SK;
    constexpr int NKS = KC / BK;

    __shared__ __align__(1024) char xbuf[2][8192];    // fp32 x tile [64][32], chunk-swizzled
    __shared__ __align__(1024) char wbuf[2][16384];   // fp16 frag-packed k-step chunk

    const int tid  = threadIdx.x;
    const int bid  = blockIdx.x;
    const int sk   = bid & (SK - 1);
    const int row0 = (bid / SK) * BM;
    const int lane = tid & 63;
    const int wv   = tid >> 6;          // 8 waves: 2M x 4N
    const int wmi  = wv >> 2;
    const int wni  = wv & 3;
    const int l15  = lane & 15;
    const int kq   = lane >> 4;

    // x staging source: thread tid fills LDS byte tid*16; swizzled chunk select
    const int xrow = tid >> 3;          // 0..63
    const int xch  = tid & 7;
    const float* xg = x + (size_t)(row0 + xrow) * DD + sk * KC
                        + ((xch ^ (xrow & 7)) << 2);
    // w staging source: linear copy of the k-step chunk
    const char* wg = wpk + (size_t)(sk * NKS) * 16384 + tid * 16;

    // wave-uniform LDS destinations
    char* xd0 = xbuf[0] + wv * 1024;  char* xd1 = xbuf[1] + wv * 1024;
    char* wa0 = wbuf[0] + wv * 1024;  char* wa1 = wbuf[1] + wv * 1024;
    char* wb0 = wbuf[0] + 8192 + wv * 1024;  char* wb1 = wbuf[1] + 8192 + wv * 1024;

    // A-frag byte offsets (swizzled), mb = 0,1 ; u = 0,1
    int xoff[2][2];
    #pragma unroll
    for (int mb = 0; mb < 2; ++mb) {
        const int r = wmi * 32 + mb * 16 + l15;
        #pragma unroll
        for (int u = 0; u < 2; ++u)
            xoff[mb][u] = r * 128 + (((kq * 2 + u) ^ (r & 7)) << 4);
    }
    // B-frag byte offsets, nb = 0,1 ; p = 0,1
    int boff[2][2];
    #pragma unroll
    for (int nb = 0; nb < 2; ++nb) {
        const int cb = wni * 2 + nb;
        #pragma unroll
        for (int p = 0; p < 2; ++p)
            boff[nb][p] = ((cb * 2 + p) * 64 + lane) * 16;
    }

    f32x4 acc00 = {0.f,0.f,0.f,0.f}, acc01 = {0.f,0.f,0.f,0.f};
    f32x4 acc10 = {0.f,0.f,0.f,0.f}, acc11 = {0.f,0.f,0.f,0.f};

    // prologue: stage tiles 0,1
    gl_lds16(xg,            xd0);
    gl_lds16(wg,            wa0);
    gl_lds16(wg + 8192,     wb0);
    gl_lds16(xg + BK,       xd1);
    gl_lds16(wg + 16384,    wa1);
    gl_lds16(wg + 16384 + 8192, wb1);
    asm volatile("s_waitcnt vmcnt(3)" ::: "memory");   // tile 0 complete
    __builtin_amdgcn_s_barrier();

    #pragma unroll 2
    for (int t = 0; t < NKS; ++t) {
        const int c = t & 1;
        const char* xb = xbuf[c];
        const char* wb = wbuf[c];

        f16x8 ah0, am0, ah1, am1;
        {
            float4 a0 = *reinterpret_cast<const float4*>(xb + xoff[0][0]);
            float4 a1 = *reinterpret_cast<const float4*>(xb + xoff[0][1]);
            float4 a2 = *reinterpret_cast<const float4*>(xb + xoff[1][0]);
            float4 a3 = *reinterpret_cast<const float4*>(xb + xoff[1][1]);
            split8(a0, a1, ah0, am0);
            split8(a2, a3, ah1, am1);
        }
        f16x8 bh0 = *reinterpret_cast<const f16x8*>(wb + boff[0][0]);
        f16x8 bm0 = *reinterpret_cast<const f16x8*>(wb + boff[0][1]);
        f16x8 bh1 = *reinterpret_cast<const f16x8*>(wb + boff[1][0]);
        f16x8 bm1 = *reinterpret_cast<const f16x8*>(wb + boff[1][1]);

        // 12 MFMAs: hh + mh + hm per (mb, nb)  (mm term ~2^-22, dropped)
        acc00 = __builtin_amdgcn_mfma_f32_16x16x32_f16(ah0, bh0, acc00, 0, 0, 0);
        acc01 = __builtin_amdgcn_mfma_f32_16x16x32_f16(ah0, bh1, acc01, 0, 0, 0);
        acc10 = __builtin_amdgcn_mfma_f32_16x16x32_f16(ah1, bh0, acc10, 0, 0, 0);
        acc11 = __builtin_amdgcn_mfma_f32_16x16x32_f16(ah1, bh1, acc11, 0, 0, 0);
        acc00 = __builtin_amdgcn_mfma_f32_16x16x32_f16(am0, bh0, acc00, 0, 0, 0);
        acc01 = __builtin_amdgcn_mfma_f32_16x16x32_f16(am0, bh1, acc01, 0, 0, 0);
        acc10 = __builtin_amdgcn_mfma_f32_16x16x32_f16(am1, bh0, acc10, 0, 0, 0);
        acc11 = __builtin_amdgcn_mfma_f32_16x16x32_f16(am1, bh1, acc11, 0, 0, 0);
        acc00 = __builtin_amdgcn_mfma_f32_16x16x32_f16(ah0, bm0, acc00, 0, 0, 0);
        acc01 = __builtin_amdgcn_mfma_f32_16x16x32_f16(ah0, bm1, acc01, 0, 0, 0);
        acc10 = __builtin_amdgcn_mfma_f32_16x16x32_f16(ah1, bm0, acc10, 0, 0, 0);
        acc11 = __builtin_amdgcn_mfma_f32_16x16x32_f16(ah1, bm1, acc11, 0, 0, 0);

        asm volatile("s_waitcnt lgkmcnt(0)" ::: "memory");
        __builtin_amdgcn_s_barrier();                  // all waves done reading buf c

        if (t + 2 < NKS) {
            const char* wsrc = wg + (size_t)(t + 2) * 16384;
            gl_lds16(xg + (size_t)(t + 2) * BK, c ? xd1 : xd0);
            gl_lds16(wsrc,        c ? wa1 : wa0);
            gl_lds16(wsrc + 8192, c ? wb1 : wb0);
            asm volatile("s_waitcnt vmcnt(3)" ::: "memory");   // tile t+1 ready
        } else {
            asm volatile("s_waitcnt vmcnt(0)" ::: "memory");   // drain tail
        }
        __builtin_amdgcn_s_barrier();
    }

    // partial logits out (deterministic, no atomics)
    const size_t pbase = ((size_t)sk * BB + row0) * 128;
    #pragma unroll
    for (int j = 0; j < 4; ++j) {
        const int r0 = wmi * 32 + kq * 4 + j;
        const int c0 = wni * 32 + l15;
        partial[pbase + (size_t)r0 * 128 + c0]           = acc00[j];
        partial[pbase + (size_t)r0 * 128 + c0 + 16]      = acc01[j];
        partial[pbase + (size_t)(r0 + 16) * 128 + c0]      = acc10[j];
        partial[pbase + (size_t)(r0 + 16) * 128 + c0 + 16] = acc11[j];
    }
}

// ------------------------------- epilogue ---------------------------------
template <int SK>
__global__ __launch_bounds__(512) void gating_epi(
    const float* __restrict__ partial,   // [SK][BB][128]
    const float* __restrict__ noise,     // [B, E]
    float* __restrict__ out)             // gates [B,E] then load [B,E]
{
    const int tid  = threadIdx.x;
    const int wv   = tid >> 6;
    const int lane = tid & 63;
    const int l15  = lane & 15;
    const int kq   = lane >> 4;
    const int grow = blockIdx.x * 32 + wv * 4 + kq;
    const int s    = l15;                // experts 4s..4s+3

    const float* pb = partial + (size_t)grow * 128 + 4 * s;
    float4 c4 = {0.f,0.f,0.f,0.f}, n4 = {0.f,0.f,0.f,0.f};
    #pragma unroll
    for (int k = 0; k < SK; ++k) {
        const float* p = pb + (size_t)k * BB * 128;
        float4 a = *reinterpret_cast<const float4*>(p);
        float4 b = *reinterpret_cast<const float4*>(p + 64);
        c4.x += a.x; c4.y += a.y; c4.z += a.z; c4.w += a.w;
        n4.x += b.x; n4.y += b.y; n4.z += b.z; n4.w += b.w;
    }

    float4 nz = *reinterpret_cast<const float4*>(noise + (size_t)grow * EE + 4 * s);

    float cc[4] = {c4.x, c4.y, c4.z, c4.w};
    float nl[4] = {n4.x, n4.y, n4.z, n4.w};
    float m1 = -3.4e38f, m2 = -3.4e38f;
    int   i1 = -1, i2 = -1;
    float cmax = -3.4e38f;
    #pragma unroll
    for (int j = 0; j < 4; ++j) {
        const int e = 4 * s + j;
        float sp  = fmaxf(nl[j], 0.0f) + log1pf(expf(-fabsf(nl[j])));  // softplus
        float nzj = (j == 0) ? nz.x : (j == 1) ? nz.y : (j == 2) ? nz.z : nz.w;
        float vno = fmaf(nzj * sp, NOISE_EPS, cc[j]);
        if (vno > m1)      { m2 = m1; i2 = i1; m1 = vno; i1 = e; }
        else if (vno > m2) { m2 = vno; i2 = e; }
        cmax = fmaxf(cmax, cc[j]);
    }

    // 16-lane reduce: top-2 with (value, lower-index) tiebreak + clean max
    #pragma unroll
    for (int m = 1; m < 16; m <<= 1) {
        float b1 = __shfl_xor(m1, m, 16);
        int  bi1 = __shfl_xor(i1, m, 16);
        float b2 = __shfl_xor(m2, m, 16);
        int  bi2 = __shfl_xor(i2, m, 16);
        cmax = fmaxf(cmax, __shfl_xor(cmax, m, 16));

        bool bwin = (b1 > m1) || (b1 == m1 && bi1 < i1);
        float t1; int ti1; float t2; int ti2;
        if (bwin) {
            t1 = b1; ti1 = bi1;
            bool aw = (m1 > b2) || (m1 == b2 && i1 < bi2);
            t2 = aw ? m1 : b2; ti2 = aw ? i1 : bi2;
        } else {
            t1 = m1; ti1 = i1;
            bool bw = (b1 > m2) || (b1 == m2 && bi1 < i2);
            t2 = bw ? b1 : m2; ti2 = bw ? bi1 : i2;
        }
        m1 = t1; i1 = ti1; m2 = t2; i2 = ti2;
    }

    float tq = expf(m2 - m1);
    float p1 = 1.0f / (1.0f + tq);
    float p2 = tq * p1;

    float e0 = expf(cc[0] - cmax);
    float e1 = expf(cc[1] - cmax);
    float e2 = expf(cc[2] - cmax);
    float e3 = expf(cc[3] - cmax);
    float sum = e0 + e1 + e2 + e3;
    #pragma unroll
    for (int m = 1; m < 16; m <<= 1) sum += __shfl_xor(sum, m, 16);
    float inv = 1.0f / sum;

    const int eb = 4 * s;
    float4 gt;
    gt.x = (eb     == i1) ? p1 : (eb     == i2) ? p2 : 0.0f;
    gt.y = (eb + 1 == i1) ? p1 : (eb + 1 == i2) ? p2 : 0.0f;
    gt.z = (eb + 2 == i1) ? p1 : (eb + 2 == i2) ? p2 : 0.0f;
    gt.w = (eb + 3 == i1) ? p1 : (eb + 3 == i2) ? p2 : 0.0f;
    float4 ld = {e0 * inv, e1 * inv, e2 * inv, e3 * inv};

    *reinterpret_cast<float4*>(out + (size_t)grow * EE + eb) = gt;
    *reinterpret_cast<float4*>(out + (size_t)BB * EE + (size_t)grow * EE + eb) = ld;
}

extern "C" void kernel_launch(void* const* d_in, const int* in_sizes, int n_in,
                              void* d_out, int out_size, void* d_ws, size_t ws_size,
                              hipStream_t stream) {
    const float* x     = (const float*)d_in[0];
    const float* gw    = (const float*)d_in[1];
    const float* ngw   = (const float*)d_in[2];
    const float* noise = (const float*)d_in[3];
    float* out = (float*)d_out;

    char*  wpk     = (char*)d_ws;                                // 2 MB packed w
    float* partial = (float*)(wpk + (size_t)2 * 1024 * 1024);    // SK * 4 MB

    const size_t MB = 1024 * 1024;

    hipLaunchKernelGGL(wsplit_pack, dim3(256), dim3(256), 0, stream, gw, ngw, wpk);

    if (ws_size >= 18 * MB) {
        hipLaunchKernelGGL(gating_main<4>, dim3((BB / BM) * 4), dim3(512), 0, stream,
                           x, wpk, partial);
        hipLaunchKernelGGL(gating_epi<4>, dim3(BB / 32), dim3(512), 0, stream,
                           partial, noise, out);
    } else if (ws_size >= 10 * MB) {
        hipLaunchKernelGGL(gating_main<2>, dim3((BB / BM) * 2), dim3(512), 0, stream,
                           x, wpk, partial);
        hipLaunchKernelGGL(gating_epi<2>, dim3(BB / 32), dim3(512), 0, stream,
                           partial, noise, out);
    } else {
        hipLaunchKernelGGL(gating_main<1>, dim3(BB / BM), dim3(512), 0, stream,
                           x, wpk, partial);
        hipLaunchKernelGGL(gating_epi<1>, dim3(BB / 32), dim3(512), 0, stream,
                           partial, noise, out);
    }
}

// Round 8
// 52.167 us; speedup vs baseline: 3.4839x; 1.0506x over previous
//
#include <hip/hip_runtime.h>
#include <math.h>

#define BB 8192
#define DD 4096
#define EE 64

constexpr float NOISE_EPS = 0.01f;
constexpr int BM  = 64;             // rows per block (main GEMM)
constexpr int BK  = 32;             // K per step (one MFMA K)

typedef __attribute__((ext_vector_type(8))) _Float16 f16x8;
typedef __attribute__((ext_vector_type(4))) float    f32x4;

__device__ __forceinline__ void split8(const float4& a, const float4& b,
                                       f16x8& hi, f16x8& mi) {
    float v[8] = {a.x, a.y, a.z, a.w, b.x, b.y, b.z, b.w};
    #pragma unroll
    for (int j = 0; j < 8; ++j) {
        _Float16 h = (_Float16)v[j];          // RN
        hi[j] = h;
        mi[j] = (_Float16)(v[j] - (float)h);
    }
}

__device__ __forceinline__ void gl_lds16(const void* g, void* l) {
    __builtin_amdgcn_global_load_lds(
        (const __attribute__((address_space(1))) unsigned*)g,
        (__attribute__((address_space(3))) unsigned*)l, 16, 0, 0);
}

// ---- pre-pass: pack weights into fp16 hi/mid planes in FRAGMENT order ----
// wpk chunk T (16 KB, T = global k-step): [cb 0..7][plane 0..1][lane 0..63] x 16B
// content(cb,p,lane): 8 fp16, weight row cb*16+(lane&15), k = T*32+(lane>>4)*8..
__global__ __launch_bounds__(256) void wsplit_pack(
    const float* __restrict__ gw, const float* __restrict__ ngw,
    char* __restrict__ wpk)
{
    const int gid = blockIdx.x * 256 + threadIdx.x;   // 65536 threads
    const int r   = gid >> 9;                         // 0..127
    const int kc  = gid & 511;                        // 8-float chunk in row
    const int k0  = kc * 8;
    const float* src = (r < EE) ? gw + (size_t)r * DD + k0
                                : ngw + (size_t)(r - EE) * DD + k0;
    float4 a = *reinterpret_cast<const float4*>(src);
    float4 b = *reinterpret_cast<const float4*>(src + 4);
    f16x8 hi, mi;
    split8(a, b, hi, mi);
    const int T    = k0 >> 5;
    const int kq   = (k0 >> 3) & 3;
    const int cb   = r >> 4;
    const int lane = kq * 16 + (r & 15);
    char* base = wpk + (size_t)T * 16384;
    *reinterpret_cast<f16x8*>(base + ((cb * 2 + 0) * 64 + lane) * 16) = hi;
    *reinterpret_cast<f16x8*>(base + ((cb * 2 + 1) * 64 + lane) * 16) = mi;
}

// ------------------------------- main GEMM --------------------------------
// 512 threads = 8 waves as 4M x 2N (each wave owns one 16-row m-block ->
// split done once per x element per wave-pair). x triple-buffered (dist-3,
// HBM cover = 2 compute phases), w double-buffered (dist-2, L2). Counted
// vmcnt(4); raw s_barrier; no vmcnt(0) in the loop.
template <int SK>
__global__ __launch_bounds__(512, 4) void gating_main(
    const float* __restrict__ x,
    const char*  __restrict__ wpk,
    float* __restrict__ partial)       // [SK][BB][128]
{
    constexpr int KC  = DD / SK;
    constexpr int NKS = KC / BK;

    __shared__ __align__(1024) char xbuf[3][8192];    // fp32 x tile [64][32], chunk-swizzled
    __shared__ __align__(1024) char wbuf[2][16384];   // fp16 frag-packed k-step chunk

    const int tid  = threadIdx.x;
    const int bid  = blockIdx.x;
    const int sk   = bid & (SK - 1);
    const int row0 = (bid / SK) * BM;
    const int lane = tid & 63;
    const int wv   = tid >> 6;          // 8 waves: 4M x 2N
    const int wmi  = wv >> 1;           // 0..3
    const int wni  = wv & 1;            // 0..1
    const int l15  = lane & 15;
    const int kq   = lane >> 4;

    // x staging source: thread tid fills LDS byte tid*16; swizzled chunk select
    const int xrow = tid >> 3;          // 0..63
    const int xch  = tid & 7;
    const float* xg = x + (size_t)(row0 + xrow) * DD + sk * KC
                        + ((xch ^ (xrow & 7)) << 2);
    // w staging source: linear copy of the k-step chunk
    const char* wg = wpk + (size_t)(sk * NKS) * 16384 + tid * 16;

    const int ldst = wv * 1024;         // wave-uniform staging dest offset

    // A-frag byte offsets (swizzled read of fp32 x rows)
    const int ar = wmi * 16 + l15;
    const int xoff0 = ar * 128 + (((kq * 2 + 0) ^ (ar & 7)) << 4);
    const int xoff1 = ar * 128 + (((kq * 2 + 1) ^ (ar & 7)) << 4);
    // B-frag byte offsets: cb = wni*4 + nb
    int boff[4][2];
    #pragma unroll
    for (int nb = 0; nb < 4; ++nb) {
        const int cb = wni * 4 + nb;
        boff[nb][0] = ((cb * 2 + 0) * 64 + lane) * 16;
        boff[nb][1] = ((cb * 2 + 1) * 64 + lane) * 16;
    }

    f32x4 acc[4];
    #pragma unroll
    for (int nb = 0; nb < 4; ++nb) acc[nb] = {0.f, 0.f, 0.f, 0.f};

    char* xc  = (char*)xbuf[0];
    char* xn1 = (char*)xbuf[1];
    char* xn2 = (char*)xbuf[2];
    char* wc  = (char*)wbuf[0];
    char* wn  = (char*)wbuf[1];

    // prologue (issue order drives the vmcnt accounting)
    gl_lds16(wg,                wc + ldst);
    gl_lds16(wg + 8192,         wc + 8192 + ldst);
    gl_lds16(xg,                xc + ldst);
    gl_lds16(wg + 16384,        wn + ldst);
    gl_lds16(wg + 16384 + 8192, wn + 8192 + ldst);
    gl_lds16(xg + BK,           xn1 + ldst);
    gl_lds16(xg + 2 * BK,       xn2 + ldst);
    asm volatile("s_waitcnt vmcnt(4)" ::: "memory");   // tile 0 (w0,x0) ready
    __builtin_amdgcn_s_barrier();

    for (int t = 0; t < NKS; ++t) {
        // ---- compute tile t from xc / wc ----
        f16x8 ah, am;
        {
            float4 a0 = *reinterpret_cast<const float4*>(xc + xoff0);
            float4 a1 = *reinterpret_cast<const float4*>(xc + xoff1);
            split8(a0, a1, ah, am);
        }
        #pragma unroll
        for (int nb = 0; nb < 4; ++nb) {
            f16x8 bh = *reinterpret_cast<const f16x8*>(wc + boff[nb][0]);
            f16x8 bm = *reinterpret_cast<const f16x8*>(wc + boff[nb][1]);
            acc[nb] = __builtin_amdgcn_mfma_f32_16x16x32_f16(ah, bh, acc[nb], 0, 0, 0);
            acc[nb] = __builtin_amdgcn_mfma_f32_16x16x32_f16(am, bh, acc[nb], 0, 0, 0);
            acc[nb] = __builtin_amdgcn_mfma_f32_16x16x32_f16(ah, bm, acc[nb], 0, 0, 0);
        }

        asm volatile("s_waitcnt lgkmcnt(0)" ::: "memory");
        __builtin_amdgcn_s_barrier();                  // buf t free for restage

        // ---- stage: w(t+2) -> wc (freed), x(t+3) -> xc (freed) ----
        const int tw = (t + 2 < NKS) ? (t + 2) : (NKS - 1);  // clamped tail keeps
        const int tx = (t + 3 < NKS) ? (t + 3) : (NKS - 1);  // vmcnt math uniform
        gl_lds16(wg + (size_t)tw * 16384,        wc + ldst);
        gl_lds16(wg + (size_t)tw * 16384 + 8192, wc + 8192 + ldst);
        gl_lds16(xg + (size_t)tx * BK,           xc + ldst);
        // outstanding (oldest first): x(t+1), w(t+1)a,b, x(t+2), w(t+2)a,b, x(t+3)
        // vmcnt(4) -> x(t+1), w(t+1) complete; x(t+2) keeps 2-phase cover
        asm volatile("s_waitcnt vmcnt(4)" ::: "memory");
        __builtin_amdgcn_s_barrier();

        // rotate buffers
        char* xt = xc; xc = xn1; xn1 = xn2; xn2 = xt;
        char* wt = wc; wc = wn;  wn  = wt;
    }
    asm volatile("s_waitcnt vmcnt(0)" ::: "memory");   // drain tail stages

    // ---- partial logits out (deterministic, no atomics) ----
    const size_t pbase = ((size_t)sk * BB + row0) * 128;
    #pragma unroll
    for (int nb = 0; nb < 4; ++nb) {
        #pragma unroll
        for (int j = 0; j < 4; ++j) {
            const int r = wmi * 16 + kq * 4 + j;
            const int c = wni * 64 + nb * 16 + l15;
            partial[pbase + (size_t)r * 128 + c] = acc[nb][j];
        }
    }
}

// ------------------------------- epilogue ---------------------------------
template <int SK>
__global__ __launch_bounds__(512) void gating_epi(
    const float* __restrict__ partial,   // [SK][BB][128]
    const float* __restrict__ noise,     // [B, E]
    float* __restrict__ out)             // gates [B,E] then load [B,E]
{
    const int tid  = threadIdx.x;
    const int wv   = tid >> 6;
    const int lane = tid & 63;
    const int l15  = lane & 15;
    const int kq   = lane >> 4;
    const int grow = blockIdx.x * 32 + wv * 4 + kq;
    const int s    = l15;                // experts 4s..4s+3

    const float* pb = partial + (size_t)grow * 128 + 4 * s;
    float4 c4 = {0.f,0.f,0.f,0.f}, n4 = {0.f,0.f,0.f,0.f};
    #pragma unroll
    for (int k = 0; k < SK; ++k) {
        const float* p = pb + (size_t)k * BB * 128;
        float4 a = *reinterpret_cast<const float4*>(p);
        float4 b = *reinterpret_cast<const float4*>(p + 64);
        c4.x += a.x; c4.y += a.y; c4.z += a.z; c4.w += a.w;
        n4.x += b.x; n4.y += b.y; n4.z += b.z; n4.w += b.w;
    }

    float4 nz = *reinterpret_cast<const float4*>(noise + (size_t)grow * EE + 4 * s);

    float cc[4] = {c4.x, c4.y, c4.z, c4.w};
    float nl[4] = {n4.x, n4.y, n4.z, n4.w};
    float m1 = -3.4e38f, m2 = -3.4e38f;
    int   i1 = -1, i2 = -1;
    float cmax = -3.4e38f;
    #pragma unroll
    for (int j = 0; j < 4; ++j) {
        const int e = 4 * s + j;
        float sp  = fmaxf(nl[j], 0.0f) + log1pf(expf(-fabsf(nl[j])));  // softplus
        float nzj = (j == 0) ? nz.x : (j == 1) ? nz.y : (j == 2) ? nz.z : nz.w;
        float vno = fmaf(nzj * sp, NOISE_EPS, cc[j]);
        if (vno > m1)      { m2 = m1; i2 = i1; m1 = vno; i1 = e; }
        else if (vno > m2) { m2 = vno; i2 = e; }
        cmax = fmaxf(cmax, cc[j]);
    }

    // 16-lane reduce: top-2 with (value, lower-index) tiebreak + clean max
    #pragma unroll
    for (int m = 1; m < 16; m <<= 1) {
        float b1 = __shfl_xor(m1, m, 16);
        int  bi1 = __shfl_xor(i1, m, 16);
        float b2 = __shfl_xor(m2, m, 16);
        int  bi2 = __shfl_xor(i2, m, 16);
        cmax = fmaxf(cmax, __shfl_xor(cmax, m, 16));

        bool bwin = (b1 > m1) || (b1 == m1 && bi1 < i1);
        float t1; int ti1; float t2; int ti2;
        if (bwin) {
            t1 = b1; ti1 = bi1;
            bool aw = (m1 > b2) || (m1 == b2 && i1 < bi2);
            t2 = aw ? m1 : b2; ti2 = aw ? i1 : bi2;
        } else {
            t1 = m1; ti1 = i1;
            bool bw = (b1 > m2) || (b1 == m2 && bi1 < i2);
            t2 = bw ? b1 : m2; ti2 = bw ? bi1 : i2;
        }
        m1 = t1; i1 = ti1; m2 = t2; i2 = ti2;
    }

    float tq = expf(m2 - m1);
    float p1 = 1.0f / (1.0f + tq);
    float p2 = tq * p1;

    float e0 = expf(cc[0] - cmax);
    float e1 = expf(cc[1] - cmax);
    float e2 = expf(cc[2] - cmax);
    float e3 = expf(cc[3] - cmax);
    float sum = e0 + e1 + e2 + e3;
    #pragma unroll
    for (int m = 1; m < 16; m <<= 1) sum += __shfl_xor(sum, m, 16);
    float inv = 1.0f / sum;

    const int eb = 4 * s;
    float4 gt;
    gt.x = (eb     == i1) ? p1 : (eb     == i2) ? p2 : 0.0f;
    gt.y = (eb + 1 == i1) ? p1 : (eb + 1 == i2) ? p2 : 0.0f;
    gt.z = (eb + 2 == i1) ? p1 : (eb + 2 == i2) ? p2 : 0.0f;
    gt.w = (eb + 3 == i1) ? p1 : (eb + 3 == i2) ? p2 : 0.0f;
    float4 ld = {e0 * inv, e1 * inv, e2 * inv, e3 * inv};

    *reinterpret_cast<float4*>(out + (size_t)grow * EE + eb) = gt;
    *reinterpret_cast<float4*>(out + (size_t)BB * EE + (size_t)grow * EE + eb) = ld;
}

extern "C" void kernel_launch(void* const* d_in, const int* in_sizes, int n_in,
                              void* d_out, int out_size, void* d_ws, size_t ws_size,
                              hipStream_t stream) {
    const float* x     = (const float*)d_in[0];
    const float* gw    = (const float*)d_in[1];
    const float* ngw   = (const float*)d_in[2];
    const float* noise = (const float*)d_in[3];
    float* out = (float*)d_out;

    char*  wpk     = (char*)d_ws;                                // 2 MB packed w
    float* partial = (float*)(wpk + (size_t)2 * 1024 * 1024);    // SK * 4 MB

    const size_t MB = 1024 * 1024;

    hipLaunchKernelGGL(wsplit_pack, dim3(256), dim3(256), 0, stream, gw, ngw, wpk);

    if (ws_size >= 18 * MB) {
        hipLaunchKernelGGL(gating_main<4>, dim3((BB / BM) * 4), dim3(512), 0, stream,
                           x, wpk, partial);
        hipLaunchKernelGGL(gating_epi<4>, dim3(BB / 32), dim3(512), 0, stream,
                           partial, noise, out);
    } else if (ws_size >= 10 * MB) {
        hipLaunchKernelGGL(gating_main<2>, dim3((BB / BM) * 2), dim3(512), 0, stream,
                           x, wpk, partial);
        hipLaunchKernelGGL(gating_epi<2>, dim3(BB / 32), dim3(512), 0, stream,
                           partial, noise, out);
    } else {
        hipLaunchKernelGGL(gating_main<1>, dim3(BB / BM), dim3(512), 0, stream,
                           x, wpk, partial);
        hipLaunchKernelGGL(gating_epi<1>, dim3(BB / 32), dim3(512), 0, stream,
                           partial, noise, out);
    }
}